// Round 15
// baseline (260.370 us; speedup 1.0000x reference)
//
#include <hip/hip_runtime.h>
#include <hip/hip_bf16.h>
#include <stdint.h>

#define CDIM 768
#define HDIM 48

typedef float  f32x4  __attribute__((ext_vector_type(4)));
typedef short  bf16x8 __attribute__((ext_vector_type(8)));
typedef unsigned short u16x4 __attribute__((ext_vector_type(4)));

__device__ __forceinline__ unsigned short f2bf(float x) {
    __hip_bfloat16 h = __float2bfloat16(x);   // HW RNE convert
    return *reinterpret_cast<unsigned short*>(&h);
}
__device__ __forceinline__ float b2f(short s) {
    union { float f; uint32_t u; } v;
    v.u = ((uint32_t)(unsigned short)s) << 16;
    return v.f;
}
#define SB0() __builtin_amdgcn_sched_barrier(0)

// ---------------- prep: pack weights into MFMA fragment order ----------------
// (unchanged — verified correct since R1)
__global__ __launch_bounds__(256) void prep_kernel(
    const float* __restrict__ W1, const float* __restrict__ b1,
    const float* __restrict__ W2,
    const float* __restrict__ gamma, const float* __restrict__ beta,
    unsigned short* __restrict__ w1p, unsigned short* __restrict__ w2p,
    float* __restrict__ b1p, float* __restrict__ cs1)
{
    const int blk = blockIdx.x, tid = threadIdx.x;
    const int l = tid & 63;
    if (blk < 18) {                       // 72 W1 frags, 4/block
        const int fid = blk * 4 + (tid >> 6);
        const int kt = fid / 3, nt = fid % 3;
        const int k0 = kt * 32 + 8 * (l >> 4);
        const int n  = nt * 16 + (l & 15);
        bf16x8 v;
        #pragma unroll
        for (int b = 0; b < 8; ++b) {
            const int k = k0 + b;
            v[b] = (short)f2bf(gamma[k] * W1[k * HDIM + n]);
        }
        *reinterpret_cast<bf16x8*>(w1p + (size_t)(fid * 64 + l) * 8) = v;
    } else if (blk < 42) {                // 96 W2 frags, 4/block
        const int fid = (blk - 18) * 4 + (tid >> 6);
        const int kt = fid / 48, nt = fid % 48;
        const int k0 = kt * 32 + 8 * (l >> 4);
        const int n  = nt * 16 + (l & 15);
        bf16x8 v;
        #pragma unroll
        for (int b = 0; b < 8; ++b) {
            const int k = k0 + b;
            const float w = (k < HDIM) ? W2[k * CDIM + n] : 0.0f;
            v[b] = (short)f2bf(w);
        }
        *reinterpret_cast<bf16x8*>(w2p + (size_t)(fid * 64 + l) * 8) = v;
    } else {                              // b1p / cs1 reductions
        const int j = tid >> 2, p = tid & 3;
        float sb = 0.f, sg = 0.f;
        if (j < HDIM) {
            for (int c = p * 192; c < (p + 1) * 192; ++c) {
                const float w = W1[c * HDIM + j];
                sb += beta[c]  * w;
                sg += gamma[c] * w;
            }
        }
        sb += __shfl_xor(sb, 1); sb += __shfl_xor(sb, 2);
        sg += __shfl_xor(sg, 1); sg += __shfl_xor(sg, 2);
        if (p == 0 && j < HDIM) { b1p[j] = b1[j] + sb; cs1[j] = sg; }
    }
}

// ---------------- main fused kernel ----------------
// R15: PRODUCER/CONSUMER WAVE SPECIALIZATION at iso-TLP with R13.
// Block = 8 waves: waves 0-3 (producers) run G1 — a pure HBM-READ stream
// (+ MFMA) writing hid tiles to LDS; waves 4-7 (consumers) run G2 — L2
// res-reads + MFMA + a pure HBM-WRITE stream. No wave ever mixes read and
// write classes in its vmcnt FIFO (R12/R14's failure: epilogue stores made
// every later load-wait inherit store-drain). Chip-wide, reads and writes
// flow CONCURRENTLY (copy µbench: 3.15+3.15 TB/s) instead of alternating in
// phase-locked steps (R13: 3.4 then 3.7, sequential). 9 barrier-paced rounds:
// consumers grab a2 frags from hid BEFORE barrier#1; producers rewrite hid
// after it (single-buffered hid, race-free). G1/G2 bodies are R13-verbatim
// (wave-contiguous 1 KB HBM instructions preserved). LDS ~148 KB -> 1
// block/CU = 8 waves/CU (same TLP as R13's 2x4).
__global__ __launch_bounds__(512, 1) void mlp_kernel(
    const float* __restrict__ x,
    const float* __restrict__ b2g,
    const unsigned short* __restrict__ w1p,
    const unsigned short* __restrict__ w2p,
    const float* __restrict__ b1p,
    const float* __restrict__ cs1,
    float* __restrict__ out)
{
    __shared__ __align__(16) char lds_xs[4][16896];            // producer x dbuf (thirds, bf16 [2][16][264])
    __shared__ __align__(16) char lds_ob[4][16640];            // consumer out stage (f32 [16][260])
    __shared__ __align__(16) unsigned short lds_hid[4][16][72];// hid handoff (single-buffered)
    __shared__ __align__(16) float lds_b2[CDIM];
    __shared__ __align__(16) float lds_b1[HDIM];
    __shared__ __align__(16) float lds_cs[HDIM];

    const int tid  = threadIdx.x;
    const int w    = tid >> 6;          // 0..7
    const int l    = tid & 63;
    const int lrow = l & 15;
    const int lg   = l >> 4;
    const int pw   = w & 3;             // role-local wave id
    const bool producer = (w < 4);

    if (tid < 192)       reinterpret_cast<f32x4*>(lds_b2)[tid]       = reinterpret_cast<const f32x4*>(b2g)[tid];
    else if (tid < 204)  reinterpret_cast<f32x4*>(lds_b1)[tid - 192] = reinterpret_cast<const f32x4*>(b1p)[tid - 192];
    else if (tid < 216)  reinterpret_cast<f32x4*>(lds_cs)[tid - 204] = reinterpret_cast<const f32x4*>(cs1)[tid - 204];
    __syncthreads();

    const bf16x8* __restrict__ w1f = reinterpret_cast<const bf16x8*>(w1p);
    const bf16x8* __restrict__ w2f = reinterpret_cast<const bf16x8*>(w2p);
    const int nb = gridDim.x;

    #pragma unroll 1
    for (int r = 0; r < 9; ++r) {
        // ---- phase A: consumers grab a2 fragments from hid (round r-1 data)
        bf16x8 a2_0, a2_1;
        if (!producer && r >= 1) {
            const unsigned short* hs = &lds_hid[pw][0][0];
            a2_0 = *reinterpret_cast<const bf16x8*>(hs + lrow * 72 + 8 * lg);
            a2_1 = *reinterpret_cast<const bf16x8*>(hs + lrow * 72 + 8 * lg + 32);
        }
        __syncthreads();   // hid reads done -> producers may overwrite

        if (producer) {
            if (r < 8) {
                // ================== G1 (R13-verbatim): pure-read stream ======
                const int t = (r * nb + blockIdx.x) * 4 + pw;
                char* const xb = lds_xs[pw];
                const char* const xg = (const char*)x + (size_t)t * 16 * 3072;
                f32x4 acc1[3];
                #pragma unroll
                for (int nt = 0; nt < 3; ++nt) { acc1[nt][0]=0.f; acc1[nt][1]=0.f; acc1[nt][2]=0.f; acc1[nt][3]=0.f; }
                float rs = 0.f, rq = 0.f;
                {   // stage third 0 (1 KB contiguous per instr)
                    f32x4 xv[16];
                    #pragma unroll
                    for (int rr = 0; rr < 16; ++rr)
                        xv[rr] = *reinterpret_cast<const f32x4*>(xg + rr * 3072 + l * 16);
                    #pragma unroll
                    for (int rr = 0; rr < 16; ++rr) {
                        u16x4 pk;
                        #pragma unroll
                        for (int e = 0; e < 4; ++e) pk[e] = f2bf(xv[rr][e]);
                        *reinterpret_cast<u16x4*>(xb + rr * 528 + l * 8) = pk;
                    }
                }
                #pragma unroll 1
                for (int j = 0; j < 3; ++j) {
                    bf16x8 w1v[24];
                    #pragma unroll
                    for (int q = 0; q < 24; ++q) w1v[q] = w1f[(j * 24 + q) * 64 + l];
                    f32x4 xn[16];
                    if (j < 2) {
                        #pragma unroll
                        for (int rr = 0; rr < 16; ++rr)
                            xn[rr] = *reinterpret_cast<const f32x4*>(xg + rr * 3072 + (j + 1) * 1024 + l * 16);
                    }
                    SB0();
                    const char* bb = xb + (j & 1) * 8448;
                    #pragma unroll
                    for (int ktl = 0; ktl < 8; ++ktl) {
                        const bf16x8 xf = *reinterpret_cast<const bf16x8*>(bb + lrow * 528 + ktl * 64 + lg * 16);
                        #pragma unroll
                        for (int e = 0; e < 8; ++e) { const float xe = b2f(xf[e]); rs += xe; rq += xe * xe; }
                        acc1[0] = __builtin_amdgcn_mfma_f32_16x16x32_bf16(w1v[ktl*3+0], xf, acc1[0], 0, 0, 0);
                        acc1[1] = __builtin_amdgcn_mfma_f32_16x16x32_bf16(w1v[ktl*3+1], xf, acc1[1], 0, 0, 0);
                        acc1[2] = __builtin_amdgcn_mfma_f32_16x16x32_bf16(w1v[ktl*3+2], xf, acc1[2], 0, 0, 0);
                    }
                    if (j < 2) {
                        char* nb2 = xb + ((j + 1) & 1) * 8448;
                        #pragma unroll
                        for (int rr = 0; rr < 16; ++rr) {
                            u16x4 pk;
                            #pragma unroll
                            for (int e = 0; e < 4; ++e) pk[e] = f2bf(xn[rr][e]);
                            *reinterpret_cast<u16x4*>(nb2 + rr * 528 + l * 8) = pk;
                        }
                    }
                }
                // ---- finalize: stats + LN + QuickGELU -> hid slot
                rs += __shfl_xor(rs, 16); rs += __shfl_xor(rs, 32);
                rq += __shfl_xor(rq, 16); rq += __shfl_xor(rq, 32);
                const float mu   = rs * (1.f / 768.f);
                const float var  = rq * (1.f / 768.f) - mu * mu;
                const float rstd = rsqrtf(var + 1e-5f);
                unsigned short* const hs = &lds_hid[pw][0][0];
                *reinterpret_cast<unsigned long long*>(hs + (l >> 2) * 72 + 48 + (l & 3) * 4) = 0ull;
                #pragma unroll
                for (int nt = 0; nt < 3; ++nt) {
                    const int c4 = nt * 16 + 4 * lg;
                    const f32x4 bb = *reinterpret_cast<const f32x4*>(&lds_b1[c4]);
                    const f32x4 cs = *reinterpret_cast<const f32x4*>(&lds_cs[c4]);
                    u16x4 pk;
                    #pragma unroll
                    for (int rr = 0; rr < 4; ++rr) {
                        const float h = rstd * (acc1[nt][rr] - mu * cs[rr]) + bb[rr];
                        const float g = h / (1.f + __expf(-1.702f * h));
                        pk[rr] = f2bf(g);
                    }
                    *reinterpret_cast<u16x4*>(hs + lrow * 72 + c4) = pk;
                }
            }
        } else if (r >= 1) {
            // ================== G2 (R13-verbatim): pure-write stream =========
            const int t = ((r - 1) * nb + blockIdx.x) * 4 + pw;
            char* const ob = lds_ob[pw];
            const size_t m0 = (size_t)t * 16;
            const float* __restrict__ xres = x + (m0 + lrow) * CDIM;
            #pragma unroll 1
            for (int t3 = 0; t3 < 3; ++t3) {
                bf16x8 w2v[32];                 // class 1: L2 fragments, oldest
                #pragma unroll
                for (int i = 0; i < 16; ++i) {
                    const int ct = t3 * 16 + i;
                    w2v[2 * i]     = w2f[ct * 64 + l];
                    w2v[2 * i + 1] = w2f[(48 + ct) * 64 + l];
                }
                f32x4 res[16];                  // class 2: L2-resident residuals
                #pragma unroll
                for (int i = 0; i < 16; ++i)
                    res[i] = *reinterpret_cast<const f32x4*>(xres + (t3 * 16 + i) * 16 + 4 * lg);
                SB0();
                #pragma unroll
                for (int i = 0; i < 16; ++i) {
                    const int ct = t3 * 16 + i;
                    f32x4 a = {0.f, 0.f, 0.f, 0.f};
                    a = __builtin_amdgcn_mfma_f32_16x16x32_bf16(w2v[2 * i],     a2_0, a, 0, 0, 0);
                    a = __builtin_amdgcn_mfma_f32_16x16x32_bf16(w2v[2 * i + 1], a2_1, a, 0, 0, 0);
                    const f32x4 bb = *reinterpret_cast<const f32x4*>(&lds_b2[ct * 16 + 4 * lg]);
                    f32x4 o;
                    #pragma unroll
                    for (int rr = 0; rr < 4; ++rr) o[rr] = a[rr] + bb[rr] + res[i][rr];
                    *reinterpret_cast<f32x4*>(ob + lrow * 1040 + (i * 16 + 4 * lg) * 4) = o;
                }
                // contiguous 1 KB stores (the wave's ONLY HBM class)
                #pragma unroll
                for (int rr = 0; rr < 16; ++rr) {
                    const f32x4 v = *reinterpret_cast<const f32x4*>(ob + rr * 1040 + l * 16);
                    *reinterpret_cast<f32x4*>((char*)out + (m0 + rr) * 3072 + t3 * 1024 + l * 16) = v;
                }
            }
        }
        __syncthreads();   // round boundary: hid(r) complete, G2(r-1) done
    }
}

extern "C" void kernel_launch(void* const* d_in, const int* in_sizes, int n_in,
                              void* d_out, int out_size, void* d_ws, size_t ws_size,
                              hipStream_t stream)
{
    const float* x     = (const float*)d_in[0];
    const float* W1    = (const float*)d_in[1];
    const float* b1    = (const float*)d_in[2];
    const float* W2    = (const float*)d_in[3];
    const float* b2    = (const float*)d_in[4];
    const float* gamma = (const float*)d_in[5];
    const float* beta  = (const float*)d_in[6];
    float* out = (float*)d_out;

    unsigned short* w1p = (unsigned short*)d_ws;     // 72 frags * 1 KB = 73728 B
    unsigned short* w2p = w1p + 24 * 3 * 64 * 8;     // 96 frags * 1 KB = 98304 B
    float* b1p = (float*)(w2p + 2 * 48 * 64 * 8);    // 48 f32
    float* cs1 = b1p + 64;                           // 48 f32 (16B-aligned gap)

    const int M = in_sizes[0] / CDIM;   // 131072 rows
    // 256 blocks x 8 waves (4 producer + 4 consumer) x 8 rounds x 4 tiles
    const int blocks = M / 16 / 4 / 8;  // 256

    prep_kernel<<<dim3(43), dim3(256), 0, stream>>>(W1, b1, W2, gamma, beta, w1p, w2p, b1p, cs1);
    mlp_kernel<<<dim3(blocks), dim3(512), 0, stream>>>(x, b2, w1p, w2p, b1p, cs1, out);
}